// Round 5
// baseline (310.836 us; speedup 1.0000x reference)
//
#include <hip/hip_runtime.h>
#include <hip/hip_bf16.h>
#include <math.h>

#define B    256
#define NIN  1152
#define IND  8
#define NOUT 10
#define OUTD 16
#define M    160          // NOUT*OUTD
#define K    9216         // NIN*IND

// ================= k_su: s partials over n-chunks ==================
// grid (CHUNKS, B/BTS), 640 threads: mt = tid%40 (m = mt*4), bl = tid/40 (0..15).
// Each thread: 2 batches (bl, bl+16), 4 output columns, loop 18 n.
// W float4 reused across the 2 batches -> 14 vmem / 128 FMA per n.
#define CHUNKS 64
#define NTOT   (NIN / CHUNKS)   // 18
#define BTS    32

template <int MODE>   // 0: c = 0.1 uniform (iter 0); 1: read cbuf (bf16)
__global__ __launch_bounds__(640, 5) void k_su(const float* __restrict__ u,
                                               const float* __restrict__ W,
                                               const __hip_bfloat16* __restrict__ cbuf,
                                               float* __restrict__ spart) {
    const int mt = threadIdx.x % 40;       // m-tile: columns mt*4 .. mt*4+3
    const int bl = threadIdx.x / 40;       // 0..15
    const int o  = mt >> 2;                // output capsule of this m-tile
    const int b  = blockIdx.y * BTS + bl;  // second batch: b+16
    const int n0 = blockIdx.x * NTOT;

    float acc0[4] = {0.f, 0.f, 0.f, 0.f};
    float acc1[4] = {0.f, 0.f, 0.f, 0.f};

    const float* up0 = u + (size_t)b * K + (size_t)n0 * IND;
    const float* up1 = up0 + (size_t)16 * K;
    const float* Wp  = W + (size_t)n0 * IND * M + mt * 4;
    const __hip_bfloat16* cp =
        MODE ? (cbuf + (size_t)o * NIN * B + (size_t)n0 * B + b) : nullptr;

#pragma unroll 2
    for (int n = 0; n < NTOT; ++n) {
        const float4 ua0 = *(const float4*)(up0 + n * IND);
        const float4 ua1 = *(const float4*)(up0 + n * IND + 4);
        const float4 ub0 = *(const float4*)(up1 + n * IND);
        const float4 ub1 = *(const float4*)(up1 + n * IND + 4);
        float c0 = 0.1f, c1 = 0.1f;
        if (MODE) {
            c0 = __bfloat162float(cp[(size_t)n * B]);
            c1 = __bfloat162float(cp[(size_t)n * B + 16]);
        }
        float cu0[8], cu1[8];
        cu0[0] = c0 * ua0.x; cu0[1] = c0 * ua0.y; cu0[2] = c0 * ua0.z; cu0[3] = c0 * ua0.w;
        cu0[4] = c0 * ua1.x; cu0[5] = c0 * ua1.y; cu0[6] = c0 * ua1.z; cu0[7] = c0 * ua1.w;
        cu1[0] = c1 * ub0.x; cu1[1] = c1 * ub0.y; cu1[2] = c1 * ub0.z; cu1[3] = c1 * ub0.w;
        cu1[4] = c1 * ub1.x; cu1[5] = c1 * ub1.y; cu1[6] = c1 * ub1.z; cu1[7] = c1 * ub1.w;
#pragma unroll
        for (int i = 0; i < IND; ++i) {
            const float4 w = *(const float4*)(Wp + (size_t)(n * IND + i) * M);
            acc0[0] = fmaf(cu0[i], w.x, acc0[0]);
            acc0[1] = fmaf(cu0[i], w.y, acc0[1]);
            acc0[2] = fmaf(cu0[i], w.z, acc0[2]);
            acc0[3] = fmaf(cu0[i], w.w, acc0[3]);
            acc1[0] = fmaf(cu1[i], w.x, acc1[0]);
            acc1[1] = fmaf(cu1[i], w.y, acc1[1]);
            acc1[2] = fmaf(cu1[i], w.z, acc1[2]);
            acc1[3] = fmaf(cu1[i], w.w, acc1[3]);
        }
    }
    float* sp = spart + (size_t)blockIdx.x * B * M + (size_t)b * M + mt * 4;
    *(float4*)sp = make_float4(acc0[0], acc0[1], acc0[2], acc0[3]);
    *(float4*)(sp + (size_t)16 * M) = make_float4(acc1[0], acc1[1], acc1[2], acc1[3]);
}

// ================= k_squash: reduce CHUNKS partials + squash ==================
// grid 640 x 64, thread per output element (b,m). Plain [b][M] output.
__global__ __launch_bounds__(64) void k_squash(const float* __restrict__ spart,
                                               float* __restrict__ dst) {
    const int gid = blockIdx.x * 64 + threadIdx.x;   // 0..40959
    float s = 0.f;
#pragma unroll 16
    for (int ch = 0; ch < CHUNKS; ++ch) s += spart[(size_t)ch * B * M + gid];
    float ss = s * s;
    ss += __shfl_xor(ss, 1);
    ss += __shfl_xor(ss, 2);
    ss += __shfl_xor(ss, 4);
    ss += __shfl_xor(ss, 8);          // sum over the 16 d-lanes (160 % 16 == 0)
    dst[gid] = s * sqrtf(ss) / (1.f + ss);
}

// ================= k_a: a = uhat . v ; b += a ; c = softmax(b) ==================
// grid (NIN/NA, B/64), 576 threads: lane = batch, wave = n. No LDS.
// W read as broadcast vector float4 (all lanes same addr -> L1 broadcast);
// v read per-lane as 4x float4 from plain [b][160] layout.
#define NA 9

template <int FIRST>
__global__ __launch_bounds__(576, 5) void k_a(const float* __restrict__ u,
                                              const float* __restrict__ W,
                                              const float* __restrict__ vbuf,
                                              float* __restrict__ blog,
                                              __hip_bfloat16* __restrict__ cbuf) {
    const int bb = threadIdx.x & 63;
    const int ng = threadIdx.x >> 6;            // 0..8, wave-uniform
    const int n  = blockIdx.x * NA + ng;
    const int gb = blockIdx.y * 64 + bb;

    float uu[IND];
    {
        const float4 u0 = *(const float4*)(u + (size_t)gb * K + (size_t)n * IND);
        const float4 u1 = *(const float4*)(u + (size_t)gb * K + (size_t)n * IND + 4);
        uu[0] = u0.x; uu[1] = u0.y; uu[2] = u0.z; uu[3] = u0.w;
        uu[4] = u1.x; uu[5] = u1.y; uu[6] = u1.z; uu[7] = u1.w;
    }
    const float* wb = W + (size_t)n * IND * M;
    const float* vp = vbuf + (size_t)gb * M;

    float a[NOUT];
#pragma unroll
    for (int o = 0; o < NOUT; ++o) {
        const float4 v0 = *(const float4*)(vp + o * OUTD);
        const float4 v1 = *(const float4*)(vp + o * OUTD + 4);
        const float4 v2 = *(const float4*)(vp + o * OUTD + 8);
        const float4 v3 = *(const float4*)(vp + o * OUTD + 12);
        float acc = 0.f;
#pragma unroll
        for (int i = 0; i < IND; ++i) {
            const float* wr = wb + (size_t)i * M + o * OUTD;
            const float4 w0 = *(const float4*)(wr);
            const float4 w1 = *(const float4*)(wr + 4);
            const float4 w2 = *(const float4*)(wr + 8);
            const float4 w3 = *(const float4*)(wr + 12);
            float wv = w0.x * v0.x + w0.y * v0.y + w0.z * v0.z + w0.w * v0.w;
            wv = fmaf(w1.x, v1.x, wv); wv = fmaf(w1.y, v1.y, wv);
            wv = fmaf(w1.z, v1.z, wv); wv = fmaf(w1.w, v1.w, wv);
            wv = fmaf(w2.x, v2.x, wv); wv = fmaf(w2.y, v2.y, wv);
            wv = fmaf(w2.z, v2.z, wv); wv = fmaf(w2.w, v2.w, wv);
            wv = fmaf(w3.x, v3.x, wv); wv = fmaf(w3.y, v3.y, wv);
            wv = fmaf(w3.z, v3.z, wv); wv = fmaf(w3.w, v3.w, wv);
            acc = fmaf(uu[i], wv, acc);
        }
        a[o] = acc;
    }

    float bl[NOUT];
    if (FIRST) {
        float* bp = blog + ((size_t)n * B + gb) * NOUT;
#pragma unroll
        for (int o = 0; o < NOUT; ++o) { bl[o] = a[o]; bp[o] = a[o]; }
    } else {
        const float* bp = blog + ((size_t)n * B + gb) * NOUT;
#pragma unroll
        for (int o = 0; o < NOUT; ++o) bl[o] = bp[o] + a[o];
    }
    float mx = bl[0];
#pragma unroll
    for (int o = 1; o < NOUT; ++o) mx = fmaxf(mx, bl[o]);
    float e[NOUT], sum = 0.f;
#pragma unroll
    for (int o = 0; o < NOUT; ++o) { e[o] = __expf(bl[o] - mx); sum += e[o]; }
    const float inv = 1.f / sum;
#pragma unroll
    for (int o = 0; o < NOUT; ++o)
        cbuf[((size_t)o * NIN + n) * B + gb] = __float2bfloat16(e[o] * inv);
}

// ================= launch ==================
extern "C" void kernel_launch(void* const* d_in, const int* in_sizes, int n_in,
                              void* d_out, int out_size, void* d_ws, size_t ws_size,
                              hipStream_t stream) {
    const float* u = (const float*)d_in[0];   // [256,1152,8]
    const float* W = (const float*)d_in[1];   // [1152,8,160]
    float* out = (float*)d_out;               // [256,10,16] f32

    float* ws    = (float*)d_ws;
    float* spart = ws;                                   // CHUNKS*B*M = 2,621,440 f (10.5 MB)
    float* vbuf  = spart + (size_t)CHUNKS * B * M;       // B*M        =    40,960 f
    float* blog  = vbuf + (size_t)B * M;                 // NIN*B*NOUT = 2,949,120 f (11.8 MB)
    __hip_bfloat16* cbuf = (__hip_bfloat16*)(blog + (size_t)NIN * B * NOUT); // 5.9 MB
    // total ~28.3 MB

    const dim3 gs(CHUNKS, B / BTS);          // (64, 8) = 512 blocks
    const dim3 ga(NIN / NA, B / 64);         // (128, 4) = 512 blocks

    // iter 0: uniform c = 0.1
    k_su<0><<<gs, 640, 0, stream>>>(u, W, cbuf, spart);
    k_squash<<<640, 64, 0, stream>>>(spart, vbuf);
    // a0 -> blog=b1, c1
    k_a<1><<<ga, 576, 0, stream>>>(u, W, vbuf, blog, cbuf);
    // s1 -> v1
    k_su<1><<<gs, 640, 0, stream>>>(u, W, cbuf, spart);
    k_squash<<<640, 64, 0, stream>>>(spart, vbuf);
    // a1 -> b2 (in-register), c2
    k_a<0><<<ga, 576, 0, stream>>>(u, W, vbuf, blog, cbuf);
    // s2 -> v2 = output
    k_su<1><<<gs, 640, 0, stream>>>(u, W, cbuf, spart);
    k_squash<<<640, 64, 0, stream>>>(spart, out);
}

// Round 6
// 250.875 us; speedup vs baseline: 1.2390x; 1.2390x over previous
//
#include <hip/hip_runtime.h>
#include <hip/hip_bf16.h>
#include <math.h>

#define B    256
#define NIN  1152
#define IND  8
#define NOUT 10
#define OUTD 16
#define M    160          // NOUT*OUTD
#define K    9216         // NIN*IND

// ================= k_su: s partials over n-chunks ==================
// grid (CHUNKS, B/BTS), 640 threads: mt = tid%40 (m = mt*4), bl = tid/40 (0..15).
// Each thread: 2 batches (bl, bl+16), 4 output columns, loop 18 n.
#define CHUNKS 64
#define NTOT   (NIN / CHUNKS)   // 18
#define BTS    32

template <int MODE>   // 0: c = 0.1 uniform (iter 0); 1: read cbuf (bf16)
__global__ __launch_bounds__(640, 5) void k_su(const float* __restrict__ u,
                                               const float* __restrict__ W,
                                               const __hip_bfloat16* __restrict__ cbuf,
                                               float* __restrict__ spart) {
    const int mt = threadIdx.x % 40;       // m-tile: columns mt*4 .. mt*4+3
    const int bl = threadIdx.x / 40;       // 0..15
    const int o  = mt >> 2;                // output capsule of this m-tile
    const int b  = blockIdx.y * BTS + bl;  // second batch: b+16
    const int n0 = blockIdx.x * NTOT;

    float acc0[4] = {0.f, 0.f, 0.f, 0.f};
    float acc1[4] = {0.f, 0.f, 0.f, 0.f};

    const float* up0 = u + (size_t)b * K + (size_t)n0 * IND;
    const float* up1 = up0 + (size_t)16 * K;
    const float* Wp  = W + (size_t)n0 * IND * M + mt * 4;
    const __hip_bfloat16* cp =
        MODE ? (cbuf + (size_t)o * NIN * B + (size_t)n0 * B + b) : nullptr;

#pragma unroll 2
    for (int n = 0; n < NTOT; ++n) {
        const float4 ua0 = *(const float4*)(up0 + n * IND);
        const float4 ua1 = *(const float4*)(up0 + n * IND + 4);
        const float4 ub0 = *(const float4*)(up1 + n * IND);
        const float4 ub1 = *(const float4*)(up1 + n * IND + 4);
        float c0 = 0.1f, c1 = 0.1f;
        if (MODE) {
            c0 = __bfloat162float(cp[(size_t)n * B]);
            c1 = __bfloat162float(cp[(size_t)n * B + 16]);
        }
        float cu0[8], cu1[8];
        cu0[0] = c0 * ua0.x; cu0[1] = c0 * ua0.y; cu0[2] = c0 * ua0.z; cu0[3] = c0 * ua0.w;
        cu0[4] = c0 * ua1.x; cu0[5] = c0 * ua1.y; cu0[6] = c0 * ua1.z; cu0[7] = c0 * ua1.w;
        cu1[0] = c1 * ub0.x; cu1[1] = c1 * ub0.y; cu1[2] = c1 * ub0.z; cu1[3] = c1 * ub0.w;
        cu1[4] = c1 * ub1.x; cu1[5] = c1 * ub1.y; cu1[6] = c1 * ub1.z; cu1[7] = c1 * ub1.w;
#pragma unroll
        for (int i = 0; i < IND; ++i) {
            const float4 w = *(const float4*)(Wp + (size_t)(n * IND + i) * M);
            acc0[0] = fmaf(cu0[i], w.x, acc0[0]);
            acc0[1] = fmaf(cu0[i], w.y, acc0[1]);
            acc0[2] = fmaf(cu0[i], w.z, acc0[2]);
            acc0[3] = fmaf(cu0[i], w.w, acc0[3]);
            acc1[0] = fmaf(cu1[i], w.x, acc1[0]);
            acc1[1] = fmaf(cu1[i], w.y, acc1[1]);
            acc1[2] = fmaf(cu1[i], w.z, acc1[2]);
            acc1[3] = fmaf(cu1[i], w.w, acc1[3]);
        }
    }
    float* sp = spart + (size_t)blockIdx.x * B * M + (size_t)b * M + mt * 4;
    *(float4*)sp = make_float4(acc0[0], acc0[1], acc0[2], acc0[3]);
    *(float4*)(sp + (size_t)16 * M) = make_float4(acc1[0], acc1[1], acc1[2], acc1[3]);
}

// ================= k_squash: reduce CHUNKS partials + squash ==================
// grid 640 x 64, thread per output element (b,m). TRANS=1 -> write vt [M][B].
template <int TRANS>
__global__ __launch_bounds__(64) void k_squash(const float* __restrict__ spart,
                                               float* __restrict__ dst) {
    const int gid = blockIdx.x * 64 + threadIdx.x;   // 0..40959
    float s = 0.f;
#pragma unroll 16
    for (int ch = 0; ch < CHUNKS; ++ch) s += spart[(size_t)ch * B * M + gid];
    float ss = s * s;
    ss += __shfl_xor(ss, 1);
    ss += __shfl_xor(ss, 2);
    ss += __shfl_xor(ss, 4);
    ss += __shfl_xor(ss, 8);          // sum over the 16 d-lanes (160 % 16 == 0)
    const float v = s * sqrtf(ss) / (1.f + ss);
    if (TRANS) {
        const int b = gid / M, m = gid % M;
        dst[(size_t)m * B + b] = v;
    } else {
        dst[gid] = v;
    }
}

// ================= k_a: a = uhat . v ; b += a ; c = softmax(b) ==================
// grid (NIN/NA, B/64), 256 threads: lane = batch, wave = n (4 n per block).
// u staged in LDS via coalesced float4 loads; v read lane-coalesced from vt [M][B];
// W read as wave-uniform broadcast float4; blog laid [n][o][b] (coalesced).
#define NA 4

template <int FIRST>
__global__ __launch_bounds__(256, 4) void k_a(const float* __restrict__ u,
                                              const float* __restrict__ W,
                                              const float* __restrict__ vt,
                                              float* __restrict__ blog,
                                              __hip_bfloat16* __restrict__ cbuf) {
    __shared__ float lds_u[64 * 33];            // 64 b-rows x 32 floats, +1 pad
    const int bb = threadIdx.x & 63;
    const int ng = threadIdx.x >> 6;            // 0..3, wave-uniform
    const int n0 = blockIdx.x * NA;
    const int n  = n0 + ng;
    const int b0 = blockIdx.y * 64;
    const int gb = b0 + bb;

    // stage u[b0..b0+63][n0*8 .. n0*8+31] -- 512 float4, coalesced 128B rows
    for (int t = threadIdx.x; t < 512; t += 256) {
        const int r = t >> 3, c = t & 7;
        const float4 q = *(const float4*)(u + (size_t)(b0 + r) * K + (size_t)n0 * IND + c * 4);
        float* dst = lds_u + r * 33 + c * 4;
        dst[0] = q.x; dst[1] = q.y; dst[2] = q.z; dst[3] = q.w;
    }
    __syncthreads();

    float uu[IND];
#pragma unroll
    for (int i = 0; i < IND; ++i) uu[i] = lds_u[bb * 33 + ng * IND + i];

    const float* wb   = W + (size_t)n * IND * M;
    const float* vcol = vt + gb;

    float a[NOUT];
#pragma unroll
    for (int o = 0; o < NOUT; ++o) {
        float vv[OUTD];
#pragma unroll
        for (int d = 0; d < OUTD; ++d) vv[d] = vcol[(size_t)(o * OUTD + d) * B];
        float acc = 0.f;
#pragma unroll
        for (int i = 0; i < IND; ++i) {
            const float* wr = wb + (size_t)i * M + o * OUTD;   // wave-uniform
            const float4 w0 = *(const float4*)(wr);
            const float4 w1 = *(const float4*)(wr + 4);
            const float4 w2 = *(const float4*)(wr + 8);
            const float4 w3 = *(const float4*)(wr + 12);
            float wv = w0.x * vv[0] + w0.y * vv[1] + w0.z * vv[2] + w0.w * vv[3];
            wv = fmaf(w1.x, vv[4], wv);  wv = fmaf(w1.y, vv[5], wv);
            wv = fmaf(w1.z, vv[6], wv);  wv = fmaf(w1.w, vv[7], wv);
            wv = fmaf(w2.x, vv[8], wv);  wv = fmaf(w2.y, vv[9], wv);
            wv = fmaf(w2.z, vv[10], wv); wv = fmaf(w2.w, vv[11], wv);
            wv = fmaf(w3.x, vv[12], wv); wv = fmaf(w3.y, vv[13], wv);
            wv = fmaf(w3.z, vv[14], wv); wv = fmaf(w3.w, vv[15], wv);
            acc = fmaf(uu[i], wv, acc);
        }
        a[o] = acc;
    }

    float bl[NOUT];
    float* bp = blog + (size_t)n * NOUT * B + gb;   // [n][o][b], coalesced per o
    if (FIRST) {
#pragma unroll
        for (int o = 0; o < NOUT; ++o) { bl[o] = a[o]; bp[(size_t)o * B] = a[o]; }
    } else {
#pragma unroll
        for (int o = 0; o < NOUT; ++o) bl[o] = bp[(size_t)o * B] + a[o];
    }
    float mx = bl[0];
#pragma unroll
    for (int o = 1; o < NOUT; ++o) mx = fmaxf(mx, bl[o]);
    float e[NOUT], sum = 0.f;
#pragma unroll
    for (int o = 0; o < NOUT; ++o) { e[o] = __expf(bl[o] - mx); sum += e[o]; }
    const float inv = 1.f / sum;
#pragma unroll
    for (int o = 0; o < NOUT; ++o)
        cbuf[((size_t)o * NIN + n) * B + gb] = __float2bfloat16(e[o] * inv);
}

// ================= launch ==================
extern "C" void kernel_launch(void* const* d_in, const int* in_sizes, int n_in,
                              void* d_out, int out_size, void* d_ws, size_t ws_size,
                              hipStream_t stream) {
    const float* u = (const float*)d_in[0];   // [256,1152,8]
    const float* W = (const float*)d_in[1];   // [1152,8,160]
    float* out = (float*)d_out;               // [256,10,16] f32

    float* ws    = (float*)d_ws;
    float* spart = ws;                                   // CHUNKS*B*M = 2,621,440 f (10.5 MB)
    float* vt    = spart + (size_t)CHUNKS * B * M;       // M*B        =    40,960 f
    float* blog  = vt + (size_t)B * M;                   // NIN*NOUT*B = 2,949,120 f (11.8 MB)
    __hip_bfloat16* cbuf = (__hip_bfloat16*)(blog + (size_t)NIN * NOUT * B); // 5.9 MB
    // total ~28.3 MB

    const dim3 gs(CHUNKS, B / BTS);          // (64, 8)  = 512 blocks
    const dim3 ga(NIN / NA, B / 64);         // (288, 4) = 1152 blocks

    // iter 0: uniform c = 0.1
    k_su<0><<<gs, 640, 0, stream>>>(u, W, cbuf, spart);
    k_squash<1><<<640, 64, 0, stream>>>(spart, vt);
    // a0 -> blog=b1, c1
    k_a<1><<<ga, 256, 0, stream>>>(u, W, vt, blog, cbuf);
    // s1 -> v1
    k_su<1><<<gs, 640, 0, stream>>>(u, W, cbuf, spart);
    k_squash<1><<<640, 64, 0, stream>>>(spart, vt);
    // a1 -> b2 (in-register), c2
    k_a<0><<<ga, 256, 0, stream>>>(u, W, vt, blog, cbuf);
    // s2 -> v2 = output
    k_su<1><<<gs, 640, 0, stream>>>(u, W, cbuf, spart);
    k_squash<0><<<640, 64, 0, stream>>>(spart, out);
}

// Round 7
// 198.941 us; speedup vs baseline: 1.5625x; 1.2611x over previous
//
#include <hip/hip_runtime.h>
#include <math.h>

#define B    256
#define NIN  1152
#define IND  8
#define NOUT 10
#define OUTD 16
#define M    160          // NOUT*OUTD
#define K    9216         // NIN*IND

typedef _Float16 h2 __attribute__((ext_vector_type(2)));
struct __align__(16) H8 { h2 h[4]; };   // 8 f16
struct __align__(8)  H4 { h2 h[2]; };   // 4 f16

#if defined(__has_builtin) && __has_builtin(__builtin_amdgcn_fdot2)
#define FDOT2(a, b, c) __builtin_amdgcn_fdot2((a), (b), (c), false)
#else
#define FDOT2(a, b, c) ((float)(a)[0] * (float)(b)[0] + (float)(a)[1] * (float)(b)[1] + (c))
#endif

// ================= k_w16: one-time W f32 -> f16 ==================
__global__ __launch_bounds__(256) void k_w16(const float* __restrict__ W,
                                             _Float16* __restrict__ Wh) {
    const int t = blockIdx.x * 256 + threadIdx.x;       // 368640 threads x4 elems
    const float4 f = *(const float4*)(W + (size_t)t * 4);
    H4 p;
    p.h[0] = h2{(_Float16)f.x, (_Float16)f.y};
    p.h[1] = h2{(_Float16)f.z, (_Float16)f.w};
    *(H4*)(Wh + (size_t)t * 4) = p;
}

// ================= k_su: s partials over n-chunks ==================
// grid (CHUNKS, B/BTS), 640 threads: mt = tid%40 (m = mt*4), bl = tid/40 (0..15).
// Each thread: 2 batches (bl, bl+16), 4 output columns, loop 18 n.
#define CHUNKS 64
#define NTOT   (NIN / CHUNKS)   // 18
#define BTS    32

template <int MODE>   // 0: c = 0.1 uniform (iter 0); 1: read cbuf (f16)
__global__ __launch_bounds__(640, 5) void k_su(const float* __restrict__ u,
                                               const float* __restrict__ W,
                                               const _Float16* __restrict__ cbuf,
                                               float* __restrict__ spart) {
    const int mt = threadIdx.x % 40;       // m-tile: columns mt*4 .. mt*4+3
    const int bl = threadIdx.x / 40;       // 0..15
    const int o  = mt >> 2;                // output capsule of this m-tile
    const int b  = blockIdx.y * BTS + bl;  // second batch: b+16
    const int n0 = blockIdx.x * NTOT;

    float acc0[4] = {0.f, 0.f, 0.f, 0.f};
    float acc1[4] = {0.f, 0.f, 0.f, 0.f};

    const float* up0 = u + (size_t)b * K + (size_t)n0 * IND;
    const float* up1 = up0 + (size_t)16 * K;
    const float* Wp  = W + (size_t)n0 * IND * M + mt * 4;
    const _Float16* cp =
        MODE ? (cbuf + (size_t)o * NIN * B + (size_t)n0 * B + b) : nullptr;

#pragma unroll 3
    for (int n = 0; n < NTOT; ++n) {
        const float4 ua0 = *(const float4*)(up0 + n * IND);
        const float4 ua1 = *(const float4*)(up0 + n * IND + 4);
        const float4 ub0 = *(const float4*)(up1 + n * IND);
        const float4 ub1 = *(const float4*)(up1 + n * IND + 4);
        float c0 = 0.1f, c1 = 0.1f;
        if (MODE) {
            c0 = (float)cp[(size_t)n * B];
            c1 = (float)cp[(size_t)n * B + 16];
        }
        float cu0[8], cu1[8];
        cu0[0] = c0 * ua0.x; cu0[1] = c0 * ua0.y; cu0[2] = c0 * ua0.z; cu0[3] = c0 * ua0.w;
        cu0[4] = c0 * ua1.x; cu0[5] = c0 * ua1.y; cu0[6] = c0 * ua1.z; cu0[7] = c0 * ua1.w;
        cu1[0] = c1 * ub0.x; cu1[1] = c1 * ub0.y; cu1[2] = c1 * ub0.z; cu1[3] = c1 * ub0.w;
        cu1[4] = c1 * ub1.x; cu1[5] = c1 * ub1.y; cu1[6] = c1 * ub1.z; cu1[7] = c1 * ub1.w;
#pragma unroll
        for (int i = 0; i < IND; ++i) {
            const float4 w = *(const float4*)(Wp + (size_t)(n * IND + i) * M);
            acc0[0] = fmaf(cu0[i], w.x, acc0[0]);
            acc0[1] = fmaf(cu0[i], w.y, acc0[1]);
            acc0[2] = fmaf(cu0[i], w.z, acc0[2]);
            acc0[3] = fmaf(cu0[i], w.w, acc0[3]);
            acc1[0] = fmaf(cu1[i], w.x, acc1[0]);
            acc1[1] = fmaf(cu1[i], w.y, acc1[1]);
            acc1[2] = fmaf(cu1[i], w.z, acc1[2]);
            acc1[3] = fmaf(cu1[i], w.w, acc1[3]);
        }
    }
    float* sp = spart + (size_t)blockIdx.x * B * M + (size_t)b * M + mt * 4;
    *(float4*)sp = make_float4(acc0[0], acc0[1], acc0[2], acc0[3]);
    *(float4*)(sp + (size_t)16 * M) = make_float4(acc1[0], acc1[1], acc1[2], acc1[3]);
}

// ================= k_squash: reduce CHUNKS partials + squash ==================
// grid 640 x 64, thread per output element (b,m). OUT16=1 -> f16 [b][160]; else f32.
template <int OUT16>
__global__ __launch_bounds__(64) void k_squash(const float* __restrict__ spart,
                                               void* __restrict__ dstv) {
    const int gid = blockIdx.x * 64 + threadIdx.x;   // 0..40959, = b*160+m
    float s = 0.f;
#pragma unroll 16
    for (int ch = 0; ch < CHUNKS; ++ch) s += spart[(size_t)ch * B * M + gid];
    float ss = s * s;
    ss += __shfl_xor(ss, 1);
    ss += __shfl_xor(ss, 2);
    ss += __shfl_xor(ss, 4);
    ss += __shfl_xor(ss, 8);          // sum over the 16 d-lanes (160 % 16 == 0)
    const float v = s * sqrtf(ss) / (1.f + ss);
    if (OUT16) ((_Float16*)dstv)[gid] = (_Float16)v;
    else       ((float*)dstv)[gid]    = v;
}

// ================= k_a: a = uhat . v ; b += a ; c = softmax(b) ==================
// grid (NIN/NA, B/64), 256 threads: lane = batch, wave = n (4 n per block).
// u staged to LDS (f32, stride 33, conflict-free); v16 rows staged to LDS
// (f16, row stride 164 ushorts = 328B -> 4-way max on b64 reads);
// W in f16, wave-uniform dwordx4 broadcast; inner dot via v_dot2_f32_f16.
#define NA 4

template <int FIRST>
__global__ __launch_bounds__(256, 4) void k_a(const float* __restrict__ u,
                                              const _Float16* __restrict__ Wh,
                                              const _Float16* __restrict__ v16,
                                              _Float16* __restrict__ blog,
                                              _Float16* __restrict__ cbuf) {
    __shared__ float  lds_u[64 * 33];     // 8448 B
    __shared__ ushort lds_v[64 * 164];    // 20992 B
    const int bb = threadIdx.x & 63;
    const int ng = threadIdx.x >> 6;            // 0..3, wave-uniform
    const int n0 = blockIdx.x * NA;
    const int n  = n0 + ng;
    const int b0 = blockIdx.y * 64;
    const int gb = b0 + bb;

    // stage u[b0..b0+63][n0*8 .. n0*8+31]: 512 float4, coalesced
    for (int t = threadIdx.x; t < 512; t += 256) {
        const int r = t >> 3, c = t & 7;
        const float4 q = *(const float4*)(u + (size_t)(b0 + r) * K + (size_t)n0 * IND + c * 4);
        float* dst = lds_u + r * 33 + c * 4;
        dst[0] = q.x; dst[1] = q.y; dst[2] = q.z; dst[3] = q.w;
    }
    // stage v16 rows [b0..b0+63][160] f16: 64 x 40 8B-segments, coalesced
    {
        const _Float16* vsrc = v16 + (size_t)b0 * M;
        for (int t = threadIdx.x; t < 64 * 40; t += 256) {
            const int r = t / 40, s = t % 40;
            const uint2 q = *(const uint2*)(vsrc + (size_t)r * M + s * 4);
            *(uint2*)(lds_v + r * 164 + s * 4) = q;
        }
    }
    __syncthreads();

    float uu[IND];
#pragma unroll
    for (int i = 0; i < IND; ++i) uu[i] = lds_u[bb * 33 + ng * IND + i];

    const _Float16* Wn = Wh + (size_t)n * (IND * M);

    float a[NOUT];
#pragma unroll
    for (int o = 0; o < NOUT; ++o) {
        const ushort* vb = lds_v + bb * 164 + o * OUTD;
        const H4 v0 = *(const H4*)(vb);
        const H4 v1 = *(const H4*)(vb + 4);
        const H4 v2 = *(const H4*)(vb + 8);
        const H4 v3 = *(const H4*)(vb + 12);
        float acc = 0.f;
#pragma unroll
        for (int i = 0; i < IND; ++i) {
            const H8* wp = (const H8*)(Wn + i * M + o * OUTD);   // wave-uniform
            const H8 w0 = wp[0];
            const H8 w1 = wp[1];
            float wv = 0.f;
            wv = FDOT2(w0.h[0], v0.h[0], wv);
            wv = FDOT2(w0.h[1], v0.h[1], wv);
            wv = FDOT2(w0.h[2], v1.h[0], wv);
            wv = FDOT2(w0.h[3], v1.h[1], wv);
            wv = FDOT2(w1.h[0], v2.h[0], wv);
            wv = FDOT2(w1.h[1], v2.h[1], wv);
            wv = FDOT2(w1.h[2], v3.h[0], wv);
            wv = FDOT2(w1.h[3], v3.h[1], wv);
            acc = fmaf(uu[i], wv, acc);
        }
        a[o] = acc;
    }

    float bl[NOUT];
    _Float16* bp = blog + (size_t)n * NOUT * B + gb;   // [n][o][b], coalesced per o
    if (FIRST) {
#pragma unroll
        for (int o = 0; o < NOUT; ++o) { bl[o] = a[o]; bp[(size_t)o * B] = (_Float16)a[o]; }
    } else {
#pragma unroll
        for (int o = 0; o < NOUT; ++o) bl[o] = (float)bp[(size_t)o * B] + a[o];
    }
    float mx = bl[0];
#pragma unroll
    for (int o = 1; o < NOUT; ++o) mx = fmaxf(mx, bl[o]);
    float e[NOUT], sum = 0.f;
#pragma unroll
    for (int o = 0; o < NOUT; ++o) { e[o] = __expf(bl[o] - mx); sum += e[o]; }
    const float inv = 1.f / sum;
#pragma unroll
    for (int o = 0; o < NOUT; ++o)
        cbuf[((size_t)o * NIN + n) * B + gb] = (_Float16)(e[o] * inv);
}

// ================= launch ==================
extern "C" void kernel_launch(void* const* d_in, const int* in_sizes, int n_in,
                              void* d_out, int out_size, void* d_ws, size_t ws_size,
                              hipStream_t stream) {
    const float* u = (const float*)d_in[0];   // [256,1152,8]
    const float* W = (const float*)d_in[1];   // [1152,8,160]
    float* out = (float*)d_out;               // [256,10,16] f32

    char* ws = (char*)d_ws;
    float*     spart = (float*)(ws);                        // 10,485,760 B
    _Float16*  blog  = (_Float16*)(ws + 10485760);          //  5,898,240 B
    _Float16*  cbuf  = (_Float16*)(ws + 16384000);          //  5,898,240 B
    _Float16*  v16   = (_Float16*)(ws + 22282240);          //     81,920 B
    _Float16*  Wh    = (_Float16*)(ws + 22364160);          //  2,949,120 B
    // total 25,313,280 B (~25.3 MB)

    const dim3 gs(CHUNKS, B / BTS);          // (64, 8)  = 512 blocks
    const dim3 ga(NIN / NA, B / 64);         // (288, 4) = 1152 blocks

    // one-time W -> f16
    k_w16<<<1440, 256, 0, stream>>>(W, Wh);

    // iter 0: uniform c = 0.1
    k_su<0><<<gs, 640, 0, stream>>>(u, W, cbuf, spart);
    k_squash<1><<<640, 64, 0, stream>>>(spart, v16);
    // a0 -> blog=b1, c1
    k_a<1><<<ga, 256, 0, stream>>>(u, Wh, v16, blog, cbuf);
    // s1 -> v1
    k_su<1><<<gs, 640, 0, stream>>>(u, W, cbuf, spart);
    k_squash<1><<<640, 64, 0, stream>>>(spart, v16);
    // a1 -> b2 (in-register), c2
    k_a<0><<<ga, 256, 0, stream>>>(u, Wh, v16, blog, cbuf);
    // s2 -> v2 = output
    k_su<1><<<gs, 640, 0, stream>>>(u, W, cbuf, spart);
    k_squash<0><<<640, 64, 0, stream>>>(spart, out);
}

// Round 8
// 164.909 us; speedup vs baseline: 1.8849x; 1.2064x over previous
//
#include <hip/hip_runtime.h>
#include <math.h>

#define B    256
#define NIN  1152
#define IND  8
#define NOUT 10
#define OUTD 16
#define M    160          // NOUT*OUTD
#define K    9216         // NIN*IND

typedef _Float16 h2 __attribute__((ext_vector_type(2)));
struct __align__(16) H8 { h2 h[4]; };   // 8 f16
struct __align__(8)  H4 { h2 h[2]; };   // 4 f16

#if defined(__has_builtin) && __has_builtin(__builtin_amdgcn_fdot2)
#define FDOT2(a, b, c) __builtin_amdgcn_fdot2((a), (b), (c), false)
#else
#define FDOT2(a, b, c) ((float)(a)[0] * (float)(b)[0] + (float)(a)[1] * (float)(b)[1] + (c))
#endif

// ================= k_w16: one-time W f32 -> f16 ==================
__global__ __launch_bounds__(256) void k_w16(const float* __restrict__ W,
                                             _Float16* __restrict__ Wh) {
    const int t = blockIdx.x * 256 + threadIdx.x;       // 368640 threads x4 elems
    const float4 f = *(const float4*)(W + (size_t)t * 4);
    H4 p;
    p.h[0] = h2{(_Float16)f.x, (_Float16)f.y};
    p.h[1] = h2{(_Float16)f.z, (_Float16)f.w};
    *(H4*)(Wh + (size_t)t * 4) = p;
}

// ================= k_su: s partials, W chunk staged in LDS ==================
// grid (CHUNKS=144, B/BT=8), 320 threads: mt = tid%40 (m-quad), bq = tid/40 (b-quad).
// Block stages W[8n][8i][160m] f32 (41 KB) once; each thread: 4 batches x 4 cols,
// loops 8 n reading W from LDS (ds_read_b128), u as broadcast L1 float4, c as 8B.
#define NCH    8
#define CHUNKS (NIN / NCH)   // 144
#define BT     32

template <int MODE>   // 0: c = 0.1 uniform (iter 0); 1: read cbuf (f16)
__global__ __launch_bounds__(320, 3) void k_su(const float* __restrict__ u,
                                               const float* __restrict__ W,
                                               const _Float16* __restrict__ cbuf,
                                               _Float16* __restrict__ spart) {
    __shared__ float Wl[NCH * IND * M];   // 40960 B
    const int mt = threadIdx.x % 40;      // m-quad: columns mt*4 .. mt*4+3
    const int bq = threadIdx.x / 40;      // 0..7: batches bq*4 .. bq*4+3
    const int o  = mt >> 2;               // output capsule of this m-quad
    const int n0 = blockIdx.x * NCH;
    const int b0 = blockIdx.y * BT;
    const int bbase = b0 + bq * 4;

    // stage W chunk: 2560 float4, coalesced
    const float* Wsrc = W + (size_t)n0 * IND * M;
    for (int t = threadIdx.x; t < NCH * IND * M / 4; t += 320) {
        const float4 q = *(const float4*)(Wsrc + (size_t)t * 4);
        *(float4*)(Wl + t * 4) = q;
    }
    __syncthreads();

    float acc[4][4];
#pragma unroll
    for (int bs = 0; bs < 4; ++bs)
#pragma unroll
        for (int j = 0; j < 4; ++j) acc[bs][j] = 0.f;

    const float* up = u + (size_t)bbase * K + (size_t)n0 * IND;
    const _Float16* cp =
        MODE ? (cbuf + ((size_t)o * NIN + n0) * B + bbase) : nullptr;

#pragma unroll
    for (int ns = 0; ns < NCH; ++ns) {
        float c4[4];
        if (MODE) {
            const H4 ch = *(const H4*)(cp + (size_t)ns * B);   // 4 f16, 8B aligned
            c4[0] = (float)ch.h[0][0]; c4[1] = (float)ch.h[0][1];
            c4[2] = (float)ch.h[1][0]; c4[3] = (float)ch.h[1][1];
        } else {
            c4[0] = c4[1] = c4[2] = c4[3] = 0.1f;
        }
        float cu[4][8];
#pragma unroll
        for (int bs = 0; bs < 4; ++bs) {
            const float4 a0 = *(const float4*)(up + (size_t)bs * K + ns * IND);
            const float4 a1 = *(const float4*)(up + (size_t)bs * K + ns * IND + 4);
            cu[bs][0] = c4[bs] * a0.x; cu[bs][1] = c4[bs] * a0.y;
            cu[bs][2] = c4[bs] * a0.z; cu[bs][3] = c4[bs] * a0.w;
            cu[bs][4] = c4[bs] * a1.x; cu[bs][5] = c4[bs] * a1.y;
            cu[bs][6] = c4[bs] * a1.z; cu[bs][7] = c4[bs] * a1.w;
        }
#pragma unroll
        for (int i = 0; i < IND; ++i) {
            const float4 w = *(const float4*)(Wl + (ns * IND + i) * M + mt * 4);
#pragma unroll
            for (int bs = 0; bs < 4; ++bs) {
                acc[bs][0] = fmaf(cu[bs][i], w.x, acc[bs][0]);
                acc[bs][1] = fmaf(cu[bs][i], w.y, acc[bs][1]);
                acc[bs][2] = fmaf(cu[bs][i], w.z, acc[bs][2]);
                acc[bs][3] = fmaf(cu[bs][i], w.w, acc[bs][3]);
            }
        }
    }
    // store f16 partials: [chunk][b][m]
    _Float16* sp = spart + ((size_t)blockIdx.x * B + bbase) * M + mt * 4;
#pragma unroll
    for (int bs = 0; bs < 4; ++bs) {
        H4 p;
        p.h[0] = h2{(_Float16)acc[bs][0], (_Float16)acc[bs][1]};
        p.h[1] = h2{(_Float16)acc[bs][2], (_Float16)acc[bs][3]};
        *(H4*)(sp + (size_t)bs * M) = p;
    }
}

// ================= k_squash: reduce CHUNKS f16 partials + squash ==================
// grid 640 x 64, thread per output element (b,m). OUT16=1 -> f16 [b][160]; else f32.
template <int OUT16>
__global__ __launch_bounds__(64) void k_squash(const _Float16* __restrict__ spart,
                                               void* __restrict__ dstv) {
    const int gid = blockIdx.x * 64 + threadIdx.x;   // 0..40959, = b*160+m
    float s = 0.f;
#pragma unroll 16
    for (int ch = 0; ch < CHUNKS; ++ch) s += (float)spart[(size_t)ch * B * M + gid];
    float ss = s * s;
    ss += __shfl_xor(ss, 1);
    ss += __shfl_xor(ss, 2);
    ss += __shfl_xor(ss, 4);
    ss += __shfl_xor(ss, 8);          // sum over the 16 d-lanes (160 % 16 == 0)
    const float v = s * sqrtf(ss) / (1.f + ss);
    if (OUT16) ((_Float16*)dstv)[gid] = (_Float16)v;
    else       ((float*)dstv)[gid]    = v;
}

// ================= k_a: a = uhat . v ; b += a ; c = softmax(b) ==================
// grid (NIN/NA, B/64), 256 threads: lane = batch, wave = n (4 n per block).
// u staged to LDS (f32, stride 33); v16 rows staged to LDS (stride 164 ushorts);
// W in f16, wave-uniform dwordx4 broadcast; inner dot via v_dot2_f32_f16.
#define NA 4

template <int FIRST>
__global__ __launch_bounds__(256, 4) void k_a(const float* __restrict__ u,
                                              const _Float16* __restrict__ Wh,
                                              const _Float16* __restrict__ v16,
                                              _Float16* __restrict__ blog,
                                              _Float16* __restrict__ cbuf) {
    __shared__ float  lds_u[64 * 33];     // 8448 B
    __shared__ ushort lds_v[64 * 164];    // 20992 B
    const int bb = threadIdx.x & 63;
    const int ng = threadIdx.x >> 6;            // 0..3, wave-uniform
    const int n0 = blockIdx.x * NA;
    const int n  = n0 + ng;
    const int b0 = blockIdx.y * 64;
    const int gb = b0 + bb;

    // stage u[b0..b0+63][n0*8 .. n0*8+31]: 512 float4, coalesced
    for (int t = threadIdx.x; t < 512; t += 256) {
        const int r = t >> 3, c = t & 7;
        const float4 q = *(const float4*)(u + (size_t)(b0 + r) * K + (size_t)n0 * IND + c * 4);
        float* dst = lds_u + r * 33 + c * 4;
        dst[0] = q.x; dst[1] = q.y; dst[2] = q.z; dst[3] = q.w;
    }
    // stage v16 rows [b0..b0+63][160] f16: 64 x 40 8B-segments, coalesced
    {
        const _Float16* vsrc = v16 + (size_t)b0 * M;
        for (int t = threadIdx.x; t < 64 * 40; t += 256) {
            const int r = t / 40, s = t % 40;
            const uint2 q = *(const uint2*)(vsrc + (size_t)r * M + s * 4);
            *(uint2*)(lds_v + r * 164 + s * 4) = q;
        }
    }
    __syncthreads();

    float uu[IND];
#pragma unroll
    for (int i = 0; i < IND; ++i) uu[i] = lds_u[bb * 33 + ng * IND + i];

    const _Float16* Wn = Wh + (size_t)n * (IND * M);

    float a[NOUT];
#pragma unroll
    for (int o = 0; o < NOUT; ++o) {
        const ushort* vb = lds_v + bb * 164 + o * OUTD;
        const H4 v0 = *(const H4*)(vb);
        const H4 v1 = *(const H4*)(vb + 4);
        const H4 v2 = *(const H4*)(vb + 8);
        const H4 v3 = *(const H4*)(vb + 12);
        float acc = 0.f;
#pragma unroll
        for (int i = 0; i < IND; ++i) {
            const H8* wp = (const H8*)(Wn + i * M + o * OUTD);   // wave-uniform
            const H8 w0 = wp[0];
            const H8 w1 = wp[1];
            float wv = 0.f;
            wv = FDOT2(w0.h[0], v0.h[0], wv);
            wv = FDOT2(w0.h[1], v0.h[1], wv);
            wv = FDOT2(w0.h[2], v1.h[0], wv);
            wv = FDOT2(w0.h[3], v1.h[1], wv);
            wv = FDOT2(w1.h[0], v2.h[0], wv);
            wv = FDOT2(w1.h[1], v2.h[1], wv);
            wv = FDOT2(w1.h[2], v3.h[0], wv);
            wv = FDOT2(w1.h[3], v3.h[1], wv);
            acc = fmaf(uu[i], wv, acc);
        }
        a[o] = acc;
    }

    float bl[NOUT];
    _Float16* bp = blog + (size_t)n * NOUT * B + gb;   // [n][o][b], coalesced per o
    if (FIRST) {
#pragma unroll
        for (int o = 0; o < NOUT; ++o) { bl[o] = a[o]; bp[(size_t)o * B] = (_Float16)a[o]; }
    } else {
#pragma unroll
        for (int o = 0; o < NOUT; ++o) bl[o] = (float)bp[(size_t)o * B] + a[o];
    }
    float mx = bl[0];
#pragma unroll
    for (int o = 1; o < NOUT; ++o) mx = fmaxf(mx, bl[o]);
    float e[NOUT], sum = 0.f;
#pragma unroll
    for (int o = 0; o < NOUT; ++o) { e[o] = __expf(bl[o] - mx); sum += e[o]; }
    const float inv = 1.f / sum;
#pragma unroll
    for (int o = 0; o < NOUT; ++o)
        cbuf[((size_t)o * NIN + n) * B + gb] = (_Float16)(e[o] * inv);
}

// ================= launch ==================
extern "C" void kernel_launch(void* const* d_in, const int* in_sizes, int n_in,
                              void* d_out, int out_size, void* d_ws, size_t ws_size,
                              hipStream_t stream) {
    const float* u = (const float*)d_in[0];   // [256,1152,8]
    const float* W = (const float*)d_in[1];   // [1152,8,160]
    float* out = (float*)d_out;               // [256,10,16] f32

    char* ws = (char*)d_ws;
    _Float16* spart = (_Float16*)(ws);                      // 11,796,480 B
    _Float16* blog  = (_Float16*)(ws + 11796480);           //  5,898,240 B
    _Float16* cbuf  = (_Float16*)(ws + 17694720);           //  5,898,240 B
    _Float16* v16   = (_Float16*)(ws + 23592960);           //     81,920 B
    _Float16* Wh    = (_Float16*)(ws + 23674880);           //  2,949,120 B
    // total 26,624,000 B (~26.6 MB)

    const dim3 gs(CHUNKS, B / BT);           // (144, 8) = 1152 blocks
    const dim3 ga(NIN / NA, B / 64);         // (288, 4) = 1152 blocks

    // one-time W -> f16
    k_w16<<<1440, 256, 0, stream>>>(W, Wh);

    // iter 0: uniform c = 0.1
    k_su<0><<<gs, 320, 0, stream>>>(u, W, cbuf, spart);
    k_squash<1><<<640, 64, 0, stream>>>(spart, v16);
    // a0 -> blog=b1, c1
    k_a<1><<<ga, 256, 0, stream>>>(u, Wh, v16, blog, cbuf);
    // s1 -> v1
    k_su<1><<<gs, 320, 0, stream>>>(u, W, cbuf, spart);
    k_squash<1><<<640, 64, 0, stream>>>(spart, v16);
    // a1 -> b2 (in-register), c2
    k_a<0><<<ga, 256, 0, stream>>>(u, Wh, v16, blog, cbuf);
    // s2 -> v2 = output
    k_su<1><<<gs, 320, 0, stream>>>(u, W, cbuf, spart);
    k_squash<0><<<640, 64, 0, stream>>>(spart, out);
}